// Round 13
// baseline (352.592 us; speedup 1.0000x reference)
//
#include <hip/hip_runtime.h>
#include <math.h>

#define BB 2
#define NN 2048
#define KK 16
#define HH 4
#define CC 8
#define PP 36
#define NEGS 0.2f
#define INVS 0.9999950000374997f  // 1/sqrt(1+1e-5)

typedef __attribute__((ext_vector_type(8))) short s16x8;
typedef __attribute__((ext_vector_type(8))) unsigned short u16x8;
typedef __attribute__((ext_vector_type(4))) float f32x4;
typedef __attribute__((ext_vector_type(16))) float f32x16;

__device__ inline unsigned short bfh(float x) {
  unsigned u = __float_as_uint(x);
  return (unsigned short)((u + 0x7FFFu + ((u >> 16) & 1u)) >> 16);
}
__device__ inline float bff(unsigned short h) {
  return __uint_as_float(((unsigned)h) << 16);
}
__device__ inline f32x4 mfma16(s16x8 a, s16x8 b, f32x4 c) {
  return __builtin_amdgcn_mfma_f32_16x16x32_bf16(a, b, c, 0, 0, 0);
}
__device__ inline f32x16 mfma32(s16x8 a, s16x8 b, f32x16 c) {
  return __builtin_amdgcn_mfma_f32_32x32x16_bf16(a, b, c, 0, 0, 0);
}

// ---------------------------------------------------------------- ball query
__global__ __launch_bounds__(256) void k_ballquery(const float* __restrict__ pos,
                                                   const int* __restrict__ types,
                                                   int* __restrict__ idxg,
                                                   int* __restrict__ acode,
                                                   float* __restrict__ rel) {
  __shared__ int s_buf[4][KK];
  const float r2 = (float)(0.08 * 0.08);
  int wslot = threadIdx.x >> 6;
  int lane = threadIdx.x & 63;
  int wg = blockIdx.x * 4 + wslot;
  int b = wg / NN, n = wg - b * NN;
  const float* pb = pos + (size_t)b * NN * 2;
  float px = pb[n * 2 + 0], py = pb[n * 2 + 1];
  float sqn = px * px + py * py;
  unsigned mask = 0u;
  int base = lane * 32;
  for (int j = 0; j < 32; ++j) {
    float qx = pb[(base + j) * 2 + 0], qy = pb[(base + j) * 2 + 1];
    float sqm = qx * qx + qy * qy;
    float d = sqn + sqm - 2.0f * (px * qx + py * qy);
    if (d <= r2) mask |= (1u << j);
  }
  int cnt = __popc(mask);
  int inc = cnt;
#pragma unroll
  for (int off = 1; off < 64; off <<= 1) {
    int v = __shfl_up(inc, off, 64);
    if (lane >= off) inc += v;
  }
  int total = __shfl(inc, 63, 64);
  int excl = inc - cnt;
  unsigned mm = mask;
  int p = excl;
  while (mm && p < KK) {
    int j = __ffs(mm) - 1;
    mm &= mm - 1u;
    s_buf[wslot][p] = base + j;
    ++p;
  }
  __syncthreads();
  int tc = total < KK ? total : KK;
  if (lane < KK) {
    int m0 = s_buf[wslot][0];
    int mk = (lane < tc) ? s_buf[wslot][lane] : m0;
    idxg[wg * KK + lane] = mk;
    int core = types[b * NN + n];
    int tg = types[b * NN + mk];
    int s0 = tg < core ? tg : core;
    int s1 = tg < core ? core : tg;
    int code = s0 * CC - (s0 * (s0 - 1)) / 2 + (s1 - s0);
    if (lane == 0 && tg < core) code = PP + core;
    acode[wg * KK + lane] = code;
    rel[(wg * KK + lane) * 2 + 0] = pb[mk * 2 + 0] - px;
    rel[(wg * KK + lane) * 2 + 1] = pb[mk * 2 + 1] - py;
  }
}

// ---------------------------------------------------------------- mega pack
// mode 0: 16-wide frag B[k][n]=src[k*srcld+n]
// mode 1: 16-wide frag B[k][n]=src[n*srcld+k]
// mode 2: 16-wide frag B[k][n]=src[n*srcld+k+Cdiff]-src[n*srcld+k]
// mode 3: flat fp32 copy (Cdiff floats, dh as float*)
// mode 4: 32-wide frag (for 32x32x16 MFMA): k=ks*16+(l>>5)*8+i, n=nt*32+(l&31),
//         B[k][n]=src[k*srcld+n]; KB=KS count, NT=NT32 count.
struct PackDesc {
  const float* src;
  unsigned short* dh;
  unsigned short* dl;
  int KB, NT, srcld, Cdiff, mode, sstride, dstride, nrep, bpr;
};
struct PackArgs {
  PackDesc d[20];
};
__global__ __launch_bounds__(256) void k_megapack(PackArgs pa) {
  PackDesc D = pa.d[blockIdx.y];
  int rep = blockIdx.x / D.bpr;
  if (rep >= D.nrep) return;
  int f = (blockIdx.x - rep * D.bpr) * 256 + threadIdx.x;
  int total = D.KB * D.NT * 64;
  if (f >= total) return;
  const float* src = D.src + (size_t)rep * D.sstride;
  unsigned short* dh = D.dh + (size_t)rep * D.dstride;
  if (D.mode == 3) {
    if (f * 8 >= D.Cdiff) return;
    float* dd = (float*)dh;
    size_t o = (size_t)f * 8;
#pragma unroll
    for (int i = 0; i < 8; ++i) dd[o + i] = src[o + i];
    return;
  }
  unsigned short* dl = D.dl + (size_t)rep * D.dstride;
  int l = f & 63;
  int t2 = f >> 6;
  size_t o = (size_t)t2 * 512 + (size_t)l * 8;
  if (D.mode == 4) {
    int nt = t2 / D.KB, ks = t2 - nt * D.KB;
    int n = nt * 32 + (l & 31);
    int k0 = ks * 16 + ((l >> 5) * 8);
#pragma unroll
    for (int i = 0; i < 8; ++i) {
      float v = src[(size_t)(k0 + i) * D.srcld + n];
      unsigned short hi = bfh(v);
      dh[o + i] = hi;
      dl[o + i] = bfh(v - bff(hi));
    }
    return;
  }
  int n = (t2 / D.KB) * 16 + (l & 15);
  int k0 = (t2 % D.KB) * 32 + ((l >> 4) * 8);
#pragma unroll
  for (int i = 0; i < 8; ++i) {
    int k = k0 + i;
    float v;
    if (D.mode == 0) {
      v = src[(size_t)k * D.srcld + n];
    } else if (D.mode == 1) {
      v = src[(size_t)n * D.srcld + k];
    } else {
      v = src[(size_t)n * D.srcld + k + D.Cdiff] - src[(size_t)n * D.srcld + k];
    }
    unsigned short hi = bfh(v);
    dh[o + i] = hi;
    dl[o + i] = bfh(v - bff(hi));
  }
}

// ---------------------------------------------------------------- pre-GEMM (merged U|V, fp32 out)
template <int KBW, int NTB>  // KBW = CIN/32
__global__ __launch_bounds__(512, 4) void k_pregemm(
    const unsigned short* __restrict__ xh, int xoff,
    const unsigned short* __restrict__ wph, const unsigned short* __restrict__ wpl,
    const float* __restrict__ scale, const float* __restrict__ bias,
    float* __restrict__ ouv, int cout) {
  constexpr int NCH = KBW / 2;
  constexpr int JT = NTB / 2;
  const int ld = 2 * cout;
  __shared__ alignas(16) char s_mem[32768];  // 2 x 16KB dbuf (hi only)
  int tid = threadIdx.x;
  int lane = tid & 63;
  int w = tid >> 6;
  int lg = lane >> 4;
  int ln = lane & 15;
  int bm = blockIdx.x;
  int ntoff = blockIdx.y * NTB;
  int wm = w >> 1, wn = w & 1;
  f32x4 acc[2][JT];
#pragma unroll
  for (int m = 0; m < 2; ++m)
#pragma unroll
    for (int j = 0; j < JT; ++j) acc[m][j] = (f32x4){0.f, 0.f, 0.f, 0.f};

  int srowg = bm * 128 + w * 16 + ln;
  const unsigned short* gH = xh + (size_t)srowg * 2048 + xoff + lg * 8;
  int wbyA = ((w * 2 + 0) * 64 + lane) * 16;
  int wbyB = ((w * 2 + 1) * 64 + lane) * 16;
  u16x8 h0, h1;
  auto load2 = [&](int ch) {
    h0 = *(const u16x8*)(gH + ch * 64);
    h1 = *(const u16x8*)(gH + ch * 64 + 32);
  };
  load2(0);
  *(u16x8*)(s_mem + wbyA) = h0;
  *(u16x8*)(s_mem + wbyB) = h1;
  __syncthreads();
  int p = 0;
  for (int ch = 0; ch < NCH; ++ch) {
    if (ch + 1 < NCH) load2(ch + 1);
#pragma unroll
    for (int ks = 0; ks < 2; ++ks) {
      s16x8 ah[2];
#pragma unroll
      for (int m = 0; m < 2; ++m) {
        int by = p * 16384 + (((wm * 2 + m) * 2 + ks) * 64 + lane) * 16;
        ah[m] = *(const s16x8*)(s_mem + by);
      }
      int kb = ch * 2 + ks;
      __builtin_amdgcn_s_setprio(1);
#pragma unroll
      for (int j = 0; j < JT; ++j) {
        size_t fo = ((size_t)(ntoff + wn * JT + j) * KBW + kb) * 64 + lane;
        s16x8 bh = ((const s16x8*)wph)[fo];
        s16x8 bl = ((const s16x8*)wpl)[fo];
#pragma unroll
        for (int m = 0; m < 2; ++m) {
          acc[m][j] = mfma16(ah[m], bh, acc[m][j]);
          acc[m][j] = mfma16(ah[m], bl, acc[m][j]);
        }
      }
      __builtin_amdgcn_s_setprio(0);
    }
    if (ch + 1 < NCH) {
      int d = (p ^ 1) * 16384;
      *(u16x8*)(s_mem + d + wbyA) = h0;
      *(u16x8*)(s_mem + d + wbyB) = h1;
      p ^= 1;
    }
    __syncthreads();
  }
#pragma unroll
  for (int j = 0; j < JT; ++j) {
    int g = (ntoff + wn * JT + j) * 16 + ln;
    int gm = g >= cout ? g - cout : g;
    float sc = scale[gm] * INVS;
    float bs = (g >= cout) ? bias[gm] : 0.f;
#pragma unroll
    for (int m = 0; m < 2; ++m) {
#pragma unroll
      for (int reg = 0; reg < 4; ++reg) {
        int row = bm * 128 + wm * 32 + m * 16 + lg * 4 + reg;
        ouv[(size_t)row * ld + g] = acc[m][j][reg] * sc + bs;
      }
    }
  }
}

// ---------------------------------------------------------------- attention phase (32x32x16)
// y in s_mem as 32x32 A-frags: frag(mt,ks) elem: row=mt*32+(l&31), k=ks*16+(l>>5)*8+i
// at ((mt*KS+ks)*64+l)*16. Block = 4 points (64 edge rows). Wave=(h, nh-half).
// C layout: col=lane&31, row=(reg&3)+8*(reg>>2)+4*(lane>>5); regs 0-7 = point mt*2,
// regs 8-15 = point mt*2+1; K-reduce = 8 in-lane adds + 1 shfl_xor(32).
template <int FOUT>
__device__ __forceinline__ void attn_phase32(
    const char* s_mem, const int* s_code, unsigned short* xh, int pgbase,
    int w, int lane, const unsigned short* __restrict__ attnh,
    const unsigned short* __restrict__ attnl, const float* __restrict__ coef,
    int ooff) {
  constexpr int KS = FOUT / 16;
  constexpr int NPASS = FOUT / 64;  // nt32 tiles per wave (wave owns FOUT/2 cols)
  int hi = lane >> 5;
  int c31 = lane & 31;
  int h = w >> 1, nh = w & 1;
  const s16x8* wph = (const s16x8*)(attnh + (size_t)h * FOUT * FOUT);
  const s16x8* wpl = (const s16x8*)(attnl + (size_t)h * FOUT * FOUT);
  const float* hb = coef + (size_t)h * 44 * FOUT;
#pragma unroll 1
  for (int pass = 0; pass < NPASS; ++pass) {
    int nt32 = nh * NPASS + pass;
    int g = nt32 * 32 + c31;
    f32x16 acc0, acc1;
#pragma unroll
    for (int i = 0; i < 16; ++i) {
      acc0[i] = 0.f;
      acc1[i] = 0.f;
    }
#pragma unroll 2
    for (int ks = 0; ks < KS; ++ks) {
      s16x8 a0 = *(const s16x8*)(s_mem + ((0 * KS + ks) * 64 + lane) * 16);
      s16x8 a1 = *(const s16x8*)(s_mem + ((1 * KS + ks) * 64 + lane) * 16);
      size_t fo = ((size_t)nt32 * KS + ks) * 64 + lane;
      s16x8 bh = wph[fo];
      s16x8 bl = wpl[fo];
      __builtin_amdgcn_s_setprio(1);
      acc0 = mfma32(a0, bh, acc0);
      acc0 = mfma32(a0, bl, acc0);
      acc1 = mfma32(a1, bh, acc1);
      acc1 = mfma32(a1, bl, acc1);
      __builtin_amdgcn_s_setprio(0);
    }
#pragma unroll 1
    for (int mt = 0; mt < 2; ++mt) {
      const f32x16& ac = mt ? acc1 : acc0;
      float e[16];
      float ssA = 0.f, ssB = 0.f;
#pragma unroll
      for (int reg = 0; reg < 16; ++reg) {
        int row = (reg & 3) + 8 * (reg >> 2) + 4 * hi;
        int code = s_code[mt * 32 + row];
        float a = hb[(size_t)code * FOUT + g];
        float ev = ac[reg] * a;
        ev = (ev >= 0.f) ? ev : NEGS * ev;
        float pe = __expf(ev);
        e[reg] = pe;
        if (reg < 8) ssA += pe; else ssB += pe;
      }
      ssA += __shfl_xor(ssA, 32, 64);
      ssB += __shfl_xor(ssB, 32, 64);
      float invA = 1.f / ssA;
      float invB = 1.f / ssB;
      float oA = 0.f, oB = 0.f;
#pragma unroll
      for (int reg = 0; reg < 16; ++reg) {
        float inv = (reg < 8) ? invA : invB;
        float u = e[reg] * inv * ac[reg];
        float t = (u > 0.f) ? u : (__expf(u) - 1.f);
        if (reg < 8) oA += t; else oB += t;
      }
      oA += __shfl_xor(oA, 32, 64);
      oB += __shfl_xor(oB, 32, 64);
      float oS = hi ? oB : oA;
      int pg = pgbase + mt * 2 + hi;
      xh[(size_t)pg * 2048 + ooff + h * FOUT + g] = bfh(oS);
    }
  }
}

// ---------------------------------------------------------------- attention layer (32x32, MT=4)
template <int FOUT>
__global__ __launch_bounds__(512, 4) void k_attn(
    unsigned short* xh, const float* __restrict__ uv,
    const int* __restrict__ idx, const int* __restrict__ acode,
    const unsigned short* __restrict__ attnh, const unsigned short* __restrict__ attnl,
    const float* __restrict__ coef, int ooff) {
  constexpr int KS = FOUT / 16;
  constexpr int YPLANE = 64 * FOUT * 2;
  constexpr int FPW = (2 * KS) / 8;  // frags per wave (>=1)
  constexpr int C2 = 2 * FOUT;

  __shared__ alignas(16) char s_mem[YPLANE];
  __shared__ int s_gsrc[64];
  __shared__ int s_code[64];

  int tid = threadIdx.x;
  int lane = tid & 63;
  int w = tid >> 6;
  int hi = lane >> 5;
  int c31 = lane & 31;
  int pgbase = blockIdx.x * 4;

  if (tid < 64) {
    int pg = pgbase + (tid >> 4);
    int b = pg >> 11;
    s_gsrc[tid] = b * 2048 + idx[pg * KK + (tid & 15)];
    s_code[tid] = acode[pg * KK + (tid & 15)];
  }
  __syncthreads();

  // stage y = leaky(U[gsrc] + V[ctr]) into 32x32 A-frags
#pragma unroll
  for (int r = 0; r < FPW; ++r) {
    int f = w * FPW + r;
    int mt = f / KS, ks = f - mt * KS;
    int row = mt * 32 + c31;
    int kcol = ks * 16 + hi * 8;
    const float* up = uv + (size_t)s_gsrc[row] * C2 + kcol;
    const float* cp = uv + (size_t)(pgbase + (row >> 4)) * C2 + FOUT + kcol;
    float4 u0 = *(const float4*)up;
    float4 u1 = *(const float4*)(up + 4);
    float4 v0 = *(const float4*)cp;
    float4 v1 = *(const float4*)(cp + 4);
    float uu[8] = {u0.x, u0.y, u0.z, u0.w, u1.x, u1.y, u1.z, u1.w};
    float vv[8] = {v0.x, v0.y, v0.z, v0.w, v1.x, v1.y, v1.z, v1.w};
    unsigned short oh[8];
#pragma unroll
    for (int i = 0; i < 8; ++i) {
      float t = uu[i] + vv[i];
      t = (t >= 0.f) ? t : NEGS * t;
      oh[i] = bfh(t);
    }
    *(u16x8*)(s_mem + (f * 64 + lane) * 16) = *(u16x8*)oh;
  }
  __syncthreads();

  attn_phase32<FOUT>(s_mem, s_code, xh, pgbase, w, lane, attnh, attnl, coef, ooff);
}

// ---------------------------------------------------------------- layer 1 (PE + conv16 + attn32)
__global__ __launch_bounds__(512, 4) void k_layer1(
    unsigned short* xh, const float* __restrict__ rel, const int* __restrict__ idx,
    const int* __restrict__ acode,
    const unsigned short* __restrict__ convh, const unsigned short* __restrict__ convl,
    const unsigned short* __restrict__ attnh, const unsigned short* __restrict__ attnl,
    const float* __restrict__ bng, const float* __restrict__ bnb,
    const float* __restrict__ coef, int ooff) {
  constexpr int FOUT = 64;
  constexpr int KB = 2;   // conv K_TOT=64 in 16-wide kb units
  constexpr int KS = 4;   // attn 32x32 k-steps
  constexpr int YPLANE = 64 * FOUT * 2;  // 8KB

  __shared__ alignas(16) char s_mem[YPLANE];
  __shared__ int s_gsrc[64];
  __shared__ int s_code[64];

  int tid = threadIdx.x;
  int lane = tid & 63;
  int w = tid >> 6;
  int lg = lane >> 4;
  int ln = lane & 15;
  int pgbase = blockIdx.x * 4;

  if (tid < 64) {
    int pg = pgbase + (tid >> 4);
    int b = pg >> 11;
    s_gsrc[tid] = b * 2048 + idx[pg * KK + (tid & 15)];
    s_code[tid] = acode[pg * KK + (tid & 15)];
  }
  __syncthreads();

  // PE staged into 16x16 frag w: lane l -> row (w>>1)*16+ln, col (w&1)*32+lg*8+i
  {
    int smt = w >> 1, skb = w & 1;
    float rc = rel[((size_t)(pgbase + smt) * KK + ln) * 2 + skb];
    unsigned short hb[8];
#pragma unroll
    for (int i = 0; i < 8; ++i) {
      int j = lg * 8 + i;
      int fidx = j & 15;
      float freq = exp2f(-(float)fidx * 0.8304820237218406f);  // 10000^(-fidx/16)
      float ang = rc * freq;
      float v = (j < 16) ? __sinf(ang) : __cosf(ang);
      hb[i] = bfh(v);
    }
    *(u16x8*)(s_mem + ((w * 64 + lane) * 16)) = *(u16x8*)hb;
  }
  __syncthreads();

  int wr = w >> 2, wc = w & 3;
  f32x4 cacc[2];
  cacc[0] = (f32x4){0.f, 0.f, 0.f, 0.f};
  cacc[1] = (f32x4){0.f, 0.f, 0.f, 0.f};
#pragma unroll
  for (int ks = 0; ks < 2; ++ks) {
    s16x8 ah[2];
#pragma unroll
    for (int m = 0; m < 2; ++m) {
      int by = (((wr * 2 + m) * 2 + ks) * 64 + lane) * 16;
      ah[m] = *(const s16x8*)(s_mem + by);
    }
    __builtin_amdgcn_s_setprio(1);
    size_t fo = ((size_t)wc * KB + ks) * 64 + lane;
    s16x8 bh = ((const s16x8*)convh)[fo];
    s16x8 bl = ((const s16x8*)convl)[fo];
#pragma unroll
    for (int m = 0; m < 2; ++m) {
      cacc[m] = mfma16(ah[m], bh, cacc[m]);
      cacc[m] = mfma16(ah[m], bl, cacc[m]);
    }
    __builtin_amdgcn_s_setprio(0);
  }
  __syncthreads();

  // conv epilogue: BN + leaky -> y written in 32x32 A-frag layout
  {
    int g = wc * 16 + ln;
    float sc = bng[g] * INVS;
    float bs = bnb[g];
#pragma unroll
    for (int m = 0; m < 2; ++m) {
#pragma unroll
      for (int reg = 0; reg < 4; ++reg) {
        int r = wr * 32 + m * 16 + lg * 4 + reg;
        float v = cacc[m][reg] * sc + bs;
        v = (v >= 0.f) ? v : NEGS * v;
        int by = (((r >> 5) * KS + (g >> 4)) * 64 + (r & 31) + 32 * ((g >> 3) & 1)) * 16 +
                 (g & 7) * 2;
        *(unsigned short*)(s_mem + by) = bfh(v);
      }
    }
  }
  __syncthreads();

  attn_phase32<64>(s_mem, s_code, xh, pgbase, w, lane, attnh, attnl, coef, ooff);
}

// ---------------------------------------------------------------- conv5 GEMM (16x16, unchanged)
__global__ __launch_bounds__(512, 2) void k_gemm5_m(const unsigned short* __restrict__ xh,
                                                    const unsigned short* __restrict__ bph,
                                                    const unsigned short* __restrict__ bpl,
                                                    const float* __restrict__ g5,
                                                    const float* __restrict__ b5,
                                                    float* __restrict__ pmax,
                                                    float* __restrict__ psum) {
  __shared__ alignas(16) char s_mem[65536];  // 2 x 32KB A dbuf
  int tid = threadIdx.x;
  int lane = tid & 63;
  int w = tid >> 6;
  int lg = lane >> 4;
  int ln = lane & 15;
  int bm = blockIdx.x, bn = blockIdx.y;
  int wm = w >> 2, wn = w & 3;
  f32x4 acc[8];
#pragma unroll
  for (int m = 0; m < 8; ++m) acc[m] = (f32x4){0.f, 0.f, 0.f, 0.f};

  int sr = w * 16 + ln;
  const unsigned short* gH = xh + (size_t)(bm * 256 + sr) * 2048 + lg * 8;
  const unsigned short* gH2 = gH + (size_t)128 * 2048;
  int fm = sr >> 4;
  int fl = lg * 16 + (sr & 15);
  int wbyA = ((fm * 2 + 0) * 64 + fl) * 16;
  int wbyB = ((fm * 2 + 1) * 64 + fl) * 16;
  int wbyC = (((fm + 8) * 2 + 0) * 64 + fl) * 16;
  int wbyD = (((fm + 8) * 2 + 1) * 64 + fl) * 16;
  u16x8 h0, h1, h2, h3;
  auto load4 = [&](int ch) {
    h0 = *(const u16x8*)(gH + ch * 64);
    h1 = *(const u16x8*)(gH + ch * 64 + 32);
    h2 = *(const u16x8*)(gH2 + ch * 64);
    h3 = *(const u16x8*)(gH2 + ch * 64 + 32);
  };
  load4(0);
  *(u16x8*)(s_mem + wbyA) = h0;
  *(u16x8*)(s_mem + wbyB) = h1;
  *(u16x8*)(s_mem + wbyC) = h2;
  *(u16x8*)(s_mem + wbyD) = h3;
  __syncthreads();
  int p = 0;
  for (int ch = 0; ch < 32; ++ch) {
    if (ch + 1 < 32) load4(ch + 1);
#pragma unroll
    for (int ks = 0; ks < 2; ++ks) {
      s16x8 ah[8];
#pragma unroll
      for (int m = 0; m < 8; ++m) {
        int by = p * 32768 + (((wm * 8 + m) * 2 + ks) * 64 + lane) * 16;
        ah[m] = *(const s16x8*)(s_mem + by);
      }
      int kb = ch * 2 + ks;
      __builtin_amdgcn_s_setprio(1);
      {
        size_t fo = ((size_t)(bn * 4 + wn) * 64 + kb) * 64 + lane;
        s16x8 bh = ((const s16x8*)bph)[fo];
        s16x8 bl = ((const s16x8*)bpl)[fo];
#pragma unroll
        for (int m = 0; m < 8; ++m) {
          acc[m] = mfma16(ah[m], bh, acc[m]);
          acc[m] = mfma16(ah[m], bl, acc[m]);
        }
      }
      __builtin_amdgcn_s_setprio(0);
    }
    if (ch + 1 < 32) {
      int d = (p ^ 1) * 32768;
      *(u16x8*)(s_mem + d + wbyA) = h0;
      *(u16x8*)(s_mem + d + wbyB) = h1;
      *(u16x8*)(s_mem + d + wbyC) = h2;
      *(u16x8*)(s_mem + d + wbyD) = h3;
      p ^= 1;
    }
    __syncthreads();
  }

  float cmax, csum;
  {
    int g = bn * 64 + wn * 16 + ln;
    float sc = g5[g] * INVS;
    float bs = b5[g];
    float mx = -3.0e38f, sm = 0.f;
#pragma unroll
    for (int m = 0; m < 8; ++m)
#pragma unroll
      for (int reg = 0; reg < 4; ++reg) {
        float v = acc[m][reg] * sc + bs;
        v = (v >= 0.f) ? v : NEGS * v;
        mx = fmaxf(mx, v);
        sm += v;
      }
    mx = fmaxf(mx, __shfl_xor(mx, 16, 64));
    mx = fmaxf(mx, __shfl_xor(mx, 32, 64));
    sm += __shfl_xor(sm, 16, 64);
    sm += __shfl_xor(sm, 32, 64);
    cmax = mx;
    csum = sm;
  }
  float* s_f = (float*)s_mem;
  if (lg == 0) {
    int col = wn * 16 + ln;
    s_f[(wm * 64 + col) * 2 + 0] = cmax;
    s_f[(wm * 64 + col) * 2 + 1] = csum;
  }
  __syncthreads();
  if (tid < 64) {
    float mx = fmaxf(s_f[tid * 2], s_f[(64 + tid) * 2]);
    float sm = s_f[tid * 2 + 1] + s_f[(64 + tid) * 2 + 1];
    pmax[(size_t)bm * 1024 + bn * 64 + tid] = mx;
    psum[(size_t)bm * 1024 + bn * 64 + tid] = sm;
  }
}

// ---------------------------------------------------------------- feat + heads
__global__ __launch_bounds__(256) void k_feat(const float* __restrict__ pmax,
                                              const float* __restrict__ psum,
                                              float* __restrict__ feat) {
  int t = blockIdx.x * 256 + threadIdx.x;
  if (t >= BB * 1024) return;
  int b = t >> 10, o = t & 1023;
  float mx = -3.0e38f, sm = 0.f;
  for (int i = 0; i < 8; ++i) {
    mx = fmaxf(mx, pmax[(size_t)(b * 8 + i) * 1024 + o]);
    sm += psum[(size_t)(b * 8 + i) * 1024 + o];
  }
  feat[b * 2048 + o] = mx;
  feat[b * 2048 + 1024 + o] = sm * (1.0f / NN);
}

template <bool HASB, bool DOBN, bool ACT>
__global__ __launch_bounds__(256) void k_head(const float* __restrict__ X,
                                              const float* __restrict__ Wm,
                                              const float* __restrict__ bias,
                                              const float* __restrict__ g,
                                              const float* __restrict__ bb,
                                              float* __restrict__ Y, int IN, int ON) {
  int gt = blockIdx.x * 256 + threadIdx.x;
  int w = gt >> 6, lane = gt & 63;
  if (w >= BB * ON) return;
  int b = w / ON, o = w - b * ON;
  const float* x = X + (size_t)b * IN;
  const float* wr = Wm + (size_t)o * IN;
  float s = 0.f;
  for (int c = lane; c < IN; c += 64) s += x[c] * wr[c];
#pragma unroll
  for (int off = 32; off > 0; off >>= 1) s += __shfl_down(s, off, 64);
  if (lane == 0) {
    if (HASB) s += bias[o];
    if (DOBN) s = s * INVS * g[o] + bb[o];
    if (ACT) s = (s >= 0.f) ? s : NEGS * s;
    Y[(size_t)b * ON + o] = s;
  }
}

// ---------------------------------------------------------------- launch
extern "C" void kernel_launch(void* const* d_in, const int* in_sizes, int n_in,
                              void* d_out, int out_size, void* d_ws, size_t ws_size,
                              hipStream_t stream) {
  const float* pos = (const float*)d_in[0];
  const int* types = (const int*)d_in[1];
  const float* conv1_w = (const float*)d_in[2];
  const float* bn1_g = (const float*)d_in[3];
  const float* bn1_b = (const float*)d_in[4];
  const float* W1 = (const float*)d_in[5];
  const float* ap1 = (const float*)d_in[6];
  const float* as1 = (const float*)d_in[7];
  const float* conv2_w = (const float*)d_in[8];
  const float* bn2_g = (const float*)d_in[9];
  const float* bn2_b = (const float*)d_in[10];
  const float* W2 = (const float*)d_in[11];
  const float* ap2 = (const float*)d_in[12];
  const float* as2 = (const float*)d_in[13];
  const float* conv3_w = (const float*)d_in[14];
  const float* bn3_g = (const float*)d_in[15];
  const float* bn3_b = (const float*)d_in[16];
  const float* W3 = (const float*)d_in[17];
  const float* ap3 = (const float*)d_in[18];
  const float* as3 = (const float*)d_in[19];
  const float* conv4_w = (const float*)d_in[20];
  const float* bn4_g = (const float*)d_in[21];
  const float* bn4_b = (const float*)d_in[22];
  const float* W4 = (const float*)d_in[23];
  const float* ap4 = (const float*)d_in[24];
  const float* as4 = (const float*)d_in[25];
  const float* conv5_w = (const float*)d_in[26];
  const float* bn5_g = (const float*)d_in[27];
  const float* bn5_b = (const float*)d_in[28];
  const float* lin1_w = (const float*)d_in[29];
  const float* bn6_g = (const float*)d_in[30];
  const float* bn6_b = (const float*)d_in[31];
  const float* lin2_w = (const float*)d_in[32];
  const float* lin2_b = (const float*)d_in[33];
  const float* bn7_g = (const float*)d_in[34];
  const float* bn7_b = (const float*)d_in[35];
  const float* lin3_w = (const float*)d_in[36];
  const float* lin3_b = (const float*)d_in[37];
  (void)in_sizes; (void)n_in; (void)out_size; (void)ws_size;

  float* ws = (float*)d_ws;
  size_t off = 0;
  auto take = [&](size_t nf) {
    float* p = ws + off;
    off += (nf + 63) & ~(size_t)63;
    return p;
  };
  auto takeu = [&](size_t nu) { return (unsigned short*)take((nu + 1) / 2); };

  int* idx = (int*)take(BB * NN * KK);
  int* acode = (int*)take(BB * NN * KK);
  float* rel = take((size_t)BB * NN * KK * 2);
  unsigned short* xh = takeu((size_t)BB * NN * 2048);
  float* uv = take((size_t)4096 * 512);
  float* pmax = take(16 * 1024);
  float* psum = take(16 * 1024);
  float* feat = take(BB * 2048);
  float* h1 = take(BB * 512);
  float* h2 = take(BB * 256);
  unsigned short* c1h = takeu(64 * 64);
  unsigned short* c1l = takeu(64 * 64);
  unsigned short* uvw2h = takeu(256 * 128);
  unsigned short* uvw2l = takeu(256 * 128);
  unsigned short* uvw3h = takeu(256 * 256);
  unsigned short* uvw3l = takeu(256 * 256);
  unsigned short* uvw4h = takeu(512 * 512);
  unsigned short* uvw4l = takeu(512 * 512);
  unsigned short* a1h = takeu(4 * 64 * 64);
  unsigned short* a1l = takeu(4 * 64 * 64);
  unsigned short* a2h = takeu(4 * 64 * 64);
  unsigned short* a2l = takeu(4 * 64 * 64);
  unsigned short* a3h = takeu(4 * 128 * 128);
  unsigned short* a3l = takeu(4 * 128 * 128);
  unsigned short* a4h = takeu(4 * 256 * 256);
  unsigned short* a4l = takeu(4 * 256 * 256);
  unsigned short* g5h = takeu((size_t)2048 * 1024);
  unsigned short* g5l = takeu((size_t)2048 * 1024);
  float* coef1 = take(4 * 44 * 64);
  float* coef2 = take(4 * 44 * 64);
  float* coef3 = take(4 * 44 * 128);
  float* coef4 = take(4 * 44 * 256);

  dim3 blk(256);
  dim3 blk5(512);

  PackArgs pa;
  // {src, dh, dl, KB, NT, srcld, Cdiff, mode, sstride, dstride, nrep, bpr}
  pa.d[0] = {conv1_w, c1h, c1l, 2, 4, 64, 0, 1, 0, 0, 1, 2};
  pa.d[1] = {conv2_w, uvw2h, uvw2l, 8, 4, 512, 0, 1, 0, 0, 1, 8};
  pa.d[2] = {conv2_w, uvw2h + 16384, uvw2l + 16384, 8, 4, 512, 256, 2, 0, 0, 1, 8};
  pa.d[3] = {conv3_w, uvw3h, uvw3l, 8, 8, 512, 0, 1, 0, 0, 1, 16};
  pa.d[4] = {conv3_w, uvw3h + 32768, uvw3l + 32768, 8, 8, 512, 256, 2, 0, 0, 1, 16};
  pa.d[5] = {conv4_w, uvw4h, uvw4l, 16, 16, 1024, 0, 1, 0, 0, 1, 64};
  pa.d[6] = {conv4_w, uvw4h + 131072, uvw4l + 131072, 16, 16, 1024, 512, 2, 0, 0, 1, 64};
  // attn weights: 32-wide fragments (mode 4); KB=KS, NT=NT32
  pa.d[7] = {W1, a1h, a1l, 4, 2, 64, 0, 4, 4096, 4096, 4, 2};
  pa.d[8] = {W2, a2h, a2l, 4, 2, 64, 0, 4, 4096, 4096, 4, 2};
  pa.d[9] = {W3, a3h, a3l, 8, 4, 128, 0, 4, 16384, 16384, 4, 8};
  pa.d[10] = {W4, a4h, a4l, 16, 8, 256, 0, 4, 65536, 65536, 4, 32};
  pa.d[11] = {conv5_w, g5h, g5l, 64, 64, 2048, 0, 1, 0, 0, 1, 1024};
  pa.d[12] = {ap1, (unsigned short*)coef1, nullptr, 5, 1, 0, 2304, 3, 2304, 5632, 4, 2};
  pa.d[13] = {as1, (unsigned short*)(coef1 + 2304), nullptr, 1, 1, 0, 512, 3, 512, 5632, 4, 1};
  pa.d[14] = {ap2, (unsigned short*)coef2, nullptr, 5, 1, 0, 2304, 3, 2304, 5632, 4, 2};
  pa.d[15] = {as2, (unsigned short*)(coef2 + 2304), nullptr, 1, 1, 0, 512, 3, 512, 5632, 4, 1};
  pa.d[16] = {ap3, (unsigned short*)coef3, nullptr, 9, 1, 0, 4608, 3, 4608, 11264, 4, 3};
  pa.d[17] = {as3, (unsigned short*)(coef3 + 4608), nullptr, 2, 1, 0, 1024, 3, 1024, 11264, 4, 1};
  pa.d[18] = {ap4, (unsigned short*)coef4, nullptr, 18, 1, 0, 9216, 3, 9216, 22528, 4, 5};
  pa.d[19] = {as4, (unsigned short*)(coef4 + 9216), nullptr, 4, 1, 0, 2048, 3, 2048, 22528, 4, 1};
  k_megapack<<<dim3(1024, 20), blk, 0, stream>>>(pa);

  k_ballquery<<<dim3(BB * NN / 4), blk, 0, stream>>>(pos, types, idx, acode, rel);

  // layer 1
  k_layer1<<<dim3(BB * NN / 4), blk5, 0, stream>>>(
      xh, rel, idx, acode, c1h, c1l, a1h, a1l, bn1_g, bn1_b, coef1, 0);

  // layer 2
  k_pregemm<8, 4><<<dim3(32, 2), blk5, 0, stream>>>(
      xh, 0, uvw2h, uvw2l, bn2_g, bn2_b, uv, 64);
  k_attn<64><<<dim3(BB * NN / 4), blk5, 0, stream>>>(
      xh, uv, idx, acode, a2h, a2l, coef2, 256);

  // layer 3
  k_pregemm<8, 8><<<dim3(32, 2), blk5, 0, stream>>>(
      xh, 256, uvw3h, uvw3l, bn3_g, bn3_b, uv, 128);
  k_attn<128><<<dim3(BB * NN / 4), blk5, 0, stream>>>(
      xh, uv, idx, acode, a3h, a3l, coef3, 512);

  // layer 4
  k_pregemm<16, 8><<<dim3(32, 4), blk5, 0, stream>>>(
      xh, 512, uvw4h, uvw4l, bn4_g, bn4_b, uv, 256);
  k_attn<256><<<dim3(BB * NN / 4), blk5, 0, stream>>>(
      xh, uv, idx, acode, a4h, a4l, coef4, 1024);

  // conv5 + pooled partials + parallel tail
  k_gemm5_m<<<dim3(16, 16), blk5, 0, stream>>>(xh, g5h, g5l, bn5_g, bn5_b, pmax, psum);
  k_feat<<<dim3(8), blk, 0, stream>>>(pmax, psum, feat);
  k_head<false, true, true><<<dim3(BB * 512 * 64 / 256), blk, 0, stream>>>(
      feat, lin1_w, nullptr, bn6_g, bn6_b, h1, 2048, 512);
  k_head<true, true, true><<<dim3(BB * 256 * 64 / 256), blk, 0, stream>>>(
      h1, lin2_w, lin2_b, bn7_g, bn7_b, h2, 512, 256);
  k_head<true, false, false><<<dim3(1), blk, 0, stream>>>(
      h2, lin3_w, lin3_b, nullptr, nullptr, (float*)d_out, 256, 2);
}

// Round 14
// 349.476 us; speedup vs baseline: 1.0089x; 1.0089x over previous
//
#include <hip/hip_runtime.h>
#include <math.h>

#define BB 2
#define NN 2048
#define KK 16
#define HH 4
#define CC 8
#define PP 36
#define NEGS 0.2f
#define INVS 0.9999950000374997f  // 1/sqrt(1+1e-5)

typedef __attribute__((ext_vector_type(8))) short s16x8;
typedef __attribute__((ext_vector_type(8))) unsigned short u16x8;
typedef __attribute__((ext_vector_type(4))) float f32x4;

__device__ inline unsigned short bfh(float x) {
  unsigned u = __float_as_uint(x);
  return (unsigned short)((u + 0x7FFFu + ((u >> 16) & 1u)) >> 16);
}
__device__ inline float bff(unsigned short h) {
  return __uint_as_float(((unsigned)h) << 16);
}
__device__ inline f32x4 mfma16(s16x8 a, s16x8 b, f32x4 c) {
  return __builtin_amdgcn_mfma_f32_16x16x32_bf16(a, b, c, 0, 0, 0);
}

// ---------------------------------------------------------------- ball query
__global__ __launch_bounds__(256) void k_ballquery(const float* __restrict__ pos,
                                                   const int* __restrict__ types,
                                                   int* __restrict__ idxg,
                                                   int* __restrict__ acode,
                                                   float* __restrict__ rel) {
  __shared__ int s_buf[4][KK];
  const float r2 = (float)(0.08 * 0.08);
  int wslot = threadIdx.x >> 6;
  int lane = threadIdx.x & 63;
  int wg = blockIdx.x * 4 + wslot;
  int b = wg / NN, n = wg - b * NN;
  const float* pb = pos + (size_t)b * NN * 2;
  float px = pb[n * 2 + 0], py = pb[n * 2 + 1];
  float sqn = px * px + py * py;
  unsigned mask = 0u;
  int base = lane * 32;
  for (int j = 0; j < 32; ++j) {
    float qx = pb[(base + j) * 2 + 0], qy = pb[(base + j) * 2 + 1];
    float sqm = qx * qx + qy * qy;
    float d = sqn + sqm - 2.0f * (px * qx + py * qy);
    if (d <= r2) mask |= (1u << j);
  }
  int cnt = __popc(mask);
  int inc = cnt;
#pragma unroll
  for (int off = 1; off < 64; off <<= 1) {
    int v = __shfl_up(inc, off, 64);
    if (lane >= off) inc += v;
  }
  int total = __shfl(inc, 63, 64);
  int excl = inc - cnt;
  unsigned mm = mask;
  int p = excl;
  while (mm && p < KK) {
    int j = __ffs(mm) - 1;
    mm &= mm - 1u;
    s_buf[wslot][p] = base + j;
    ++p;
  }
  __syncthreads();
  int tc = total < KK ? total : KK;
  if (lane < KK) {
    int m0 = s_buf[wslot][0];
    int mk = (lane < tc) ? s_buf[wslot][lane] : m0;
    idxg[wg * KK + lane] = mk;
    int core = types[b * NN + n];
    int tg = types[b * NN + mk];
    int s0 = tg < core ? tg : core;
    int s1 = tg < core ? core : tg;
    int code = s0 * CC - (s0 * (s0 - 1)) / 2 + (s1 - s0);
    if (lane == 0 && tg < core) code = PP + core;
    acode[wg * KK + lane] = code;
    rel[(wg * KK + lane) * 2 + 0] = pb[mk * 2 + 0] - px;
    rel[(wg * KK + lane) * 2 + 1] = pb[mk * 2 + 1] - py;
  }
}

// ---------------------------------------------------------------- mega pack
struct PackDesc {
  const float* src;
  unsigned short* dh;
  unsigned short* dl;
  int KB, NT, srcld, Cdiff, mode, sstride, dstride, nrep, bpr;
};
struct PackArgs {
  PackDesc d[20];
};
__global__ __launch_bounds__(256) void k_megapack(PackArgs pa) {
  PackDesc D = pa.d[blockIdx.y];
  int rep = blockIdx.x / D.bpr;
  if (rep >= D.nrep) return;
  int f = (blockIdx.x - rep * D.bpr) * 256 + threadIdx.x;
  int total = D.KB * D.NT * 64;
  if (f >= total) return;
  const float* src = D.src + (size_t)rep * D.sstride;
  unsigned short* dh = D.dh + (size_t)rep * D.dstride;
  if (D.mode == 3) {
    if (f * 8 >= D.Cdiff) return;
    float* dd = (float*)dh;
    size_t o = (size_t)f * 8;
#pragma unroll
    for (int i = 0; i < 8; ++i) dd[o + i] = src[o + i];
    return;
  }
  unsigned short* dl = D.dl + (size_t)rep * D.dstride;
  int l = f & 63;
  int t2 = f >> 6;
  int n = (t2 / D.KB) * 16 + (l & 15);
  int k0 = (t2 % D.KB) * 32 + ((l >> 4) * 8);
  size_t o = (size_t)t2 * 512 + (size_t)l * 8;
#pragma unroll
  for (int i = 0; i < 8; ++i) {
    int k = k0 + i;
    float v;
    if (D.mode == 0) {
      v = src[(size_t)k * D.srcld + n];
    } else if (D.mode == 1) {
      v = src[(size_t)n * D.srcld + k];
    } else {
      v = src[(size_t)n * D.srcld + k + D.Cdiff] - src[(size_t)n * D.srcld + k];
    }
    unsigned short hi = bfh(v);
    dh[o + i] = hi;
    dl[o + i] = bfh(v - bff(hi));
  }
}

// ---------------------------------------------------------------- pre-GEMM (merged U|V, fp32 out)
template <int KBW, int NTB>  // KBW = CIN/32
__global__ __launch_bounds__(512, 4) void k_pregemm(
    const unsigned short* __restrict__ xh, int xoff,
    const unsigned short* __restrict__ wph, const unsigned short* __restrict__ wpl,
    const float* __restrict__ scale, const float* __restrict__ bias,
    float* __restrict__ ouv, int cout) {
  constexpr int NCH = KBW / 2;
  constexpr int JT = NTB / 2;
  const int ld = 2 * cout;
  __shared__ alignas(16) char s_mem[32768];  // 2 x 16KB dbuf (hi only)
  int tid = threadIdx.x;
  int lane = tid & 63;
  int w = tid >> 6;
  int lg = lane >> 4;
  int ln = lane & 15;
  int bm = blockIdx.x;
  int ntoff = blockIdx.y * NTB;
  int wm = w >> 1, wn = w & 1;
  f32x4 acc[2][JT];
#pragma unroll
  for (int m = 0; m < 2; ++m)
#pragma unroll
    for (int j = 0; j < JT; ++j) acc[m][j] = (f32x4){0.f, 0.f, 0.f, 0.f};

  int srowg = bm * 128 + w * 16 + ln;
  const unsigned short* gH = xh + (size_t)srowg * 2048 + xoff + lg * 8;
  int wbyA = ((w * 2 + 0) * 64 + lane) * 16;
  int wbyB = ((w * 2 + 1) * 64 + lane) * 16;
  u16x8 h0, h1;
  auto load2 = [&](int ch) {
    h0 = *(const u16x8*)(gH + ch * 64);
    h1 = *(const u16x8*)(gH + ch * 64 + 32);
  };
  load2(0);
  *(u16x8*)(s_mem + wbyA) = h0;
  *(u16x8*)(s_mem + wbyB) = h1;
  __syncthreads();
  int p = 0;
  for (int ch = 0; ch < NCH; ++ch) {
    if (ch + 1 < NCH) load2(ch + 1);
#pragma unroll
    for (int ks = 0; ks < 2; ++ks) {
      s16x8 ah[2];
#pragma unroll
      for (int m = 0; m < 2; ++m) {
        int by = p * 16384 + (((wm * 2 + m) * 2 + ks) * 64 + lane) * 16;
        ah[m] = *(const s16x8*)(s_mem + by);
      }
      int kb = ch * 2 + ks;
      __builtin_amdgcn_s_setprio(1);
#pragma unroll
      for (int j = 0; j < JT; ++j) {
        size_t fo = ((size_t)(ntoff + wn * JT + j) * KBW + kb) * 64 + lane;
        s16x8 bh = ((const s16x8*)wph)[fo];
        s16x8 bl = ((const s16x8*)wpl)[fo];
#pragma unroll
        for (int m = 0; m < 2; ++m) {
          acc[m][j] = mfma16(ah[m], bh, acc[m][j]);
          acc[m][j] = mfma16(ah[m], bl, acc[m][j]);
        }
      }
      __builtin_amdgcn_s_setprio(0);
    }
    if (ch + 1 < NCH) {
      int d = (p ^ 1) * 16384;
      *(u16x8*)(s_mem + d + wbyA) = h0;
      *(u16x8*)(s_mem + d + wbyB) = h1;
      p ^= 1;
    }
    __syncthreads();
  }
#pragma unroll
  for (int j = 0; j < JT; ++j) {
    int g = (ntoff + wn * JT + j) * 16 + ln;
    int gm = g >= cout ? g - cout : g;
    float sc = scale[gm] * INVS;
    float bs = (g >= cout) ? bias[gm] : 0.f;
#pragma unroll
    for (int m = 0; m < 2; ++m) {
#pragma unroll
      for (int reg = 0; reg < 4; ++reg) {
        int row = bm * 128 + wm * 32 + m * 16 + lg * 4 + reg;
        ouv[(size_t)row * ld + g] = acc[m][j][reg] * sc + bs;
      }
    }
  }
}

// ---------------------------------------------------------------- attention phase (shared)
// MT points per block (MT*16 edge rows). JW=1 for MT=8 (B-pair feeds 16 MFMAs).
template <int FOUT, int MT>
__device__ __forceinline__ void attn_phase(
    const char* s_mem, const int* s_code, unsigned short* xh, int pgbase,
    int w, int lane, const unsigned short* __restrict__ attnh,
    const unsigned short* __restrict__ attnl, const float* __restrict__ coef,
    int ooff) {
  constexpr int KBA = FOUT / 32;
  constexpr int NT = FOUT / 16;
  constexpr int NTW_A = NT / 2;
  constexpr int JW = (MT == 8) ? 1 : ((NTW_A > 2) ? 2 : NTW_A);
  constexpr int NPASS = NTW_A / JW;
  int lg = lane >> 4;
  int ln = lane & 15;
  int h = w >> 1, nh = w & 1;
  const s16x8* wph = (const s16x8*)(attnh + (size_t)h * FOUT * FOUT);
  const s16x8* wpl = (const s16x8*)(attnl + (size_t)h * FOUT * FOUT);
  const float* hb = coef + (size_t)h * 44 * FOUT + ln;
#pragma unroll 1
  for (int pass = 0; pass < NPASS; ++pass) {
    float ac[MT][JW][4];
#pragma unroll
    for (int m = 0; m < MT; ++m)
#pragma unroll
      for (int reg = 0; reg < 4; ++reg) {
        int off = s_code[m * 16 + lg * 4 + reg] * FOUT;
#pragma unroll
        for (int j = 0; j < JW; ++j) {
          int nt = nh * NTW_A + pass * JW + j;
          ac[m][j][reg] = hb[off + nt * 16];
        }
      }
    f32x4 aacc[MT][JW];
#pragma unroll
    for (int m = 0; m < MT; ++m)
#pragma unroll
      for (int j = 0; j < JW; ++j) aacc[m][j] = (f32x4){0.f, 0.f, 0.f, 0.f};
#pragma unroll 2
    for (int kb = 0; kb < KBA; ++kb) {
      s16x8 ah[MT];
#pragma unroll
      for (int m = 0; m < MT; ++m) {
        int by = ((m * KBA + kb) * 64 + lane) * 16;
        ah[m] = *(const s16x8*)(s_mem + by);
      }
      __builtin_amdgcn_s_setprio(1);
#pragma unroll
      for (int j = 0; j < JW; ++j) {
        int nt = nh * NTW_A + pass * JW + j;
        size_t fo = ((size_t)nt * KBA + kb) * 64 + lane;
        s16x8 bh = wph[fo];
        s16x8 bl = wpl[fo];
#pragma unroll
        for (int m = 0; m < MT; ++m) {
          aacc[m][j] = mfma16(ah[m], bh, aacc[m][j]);
          aacc[m][j] = mfma16(ah[m], bl, aacc[m][j]);
        }
      }
      __builtin_amdgcn_s_setprio(0);
    }
#pragma unroll
    for (int m = 0; m < MT; ++m) {
      int pg = pgbase + m;
#pragma unroll
      for (int j = 0; j < JW; ++j) {
        int nt = nh * NTW_A + pass * JW + j;
        int g = nt * 16 + ln;
        float e[4];
        float ssum = 0.f;
#pragma unroll
        for (int reg = 0; reg < 4; ++reg) {
          float ev = aacc[m][j][reg] * ac[m][j][reg];
          ev = (ev >= 0.f) ? ev : NEGS * ev;
          float pe = __expf(ev);
          e[reg] = pe;
          ssum += pe;
        }
        ssum += __shfl_xor(ssum, 16, 64);
        ssum += __shfl_xor(ssum, 32, 64);
        float inv = 1.f / ssum;
        float o = 0.f;
#pragma unroll
        for (int reg = 0; reg < 4; ++reg) {
          float u = e[reg] * inv * aacc[m][j][reg];
          o += (u > 0.f) ? u : (__expf(u) - 1.f);
        }
        o += __shfl_xor(o, 16, 64);
        o += __shfl_xor(o, 32, 64);
        if (lane < 16) {
          xh[(size_t)pg * 2048 + ooff + h * FOUT + g] = bfh(o);
        }
      }
    }
  }
}

// ---------------------------------------------------------------- attention layer (MT=8)
template <int FOUT>
__global__ __launch_bounds__(512, 4) void k_attn(
    unsigned short* xh, const float* __restrict__ uv,
    const int* __restrict__ idx, const int* __restrict__ acode,
    const unsigned short* __restrict__ attnh, const unsigned short* __restrict__ attnl,
    const float* __restrict__ coef, int ooff) {
  constexpr int MT = 8;
  constexpr int KBA = FOUT / 32;
  constexpr int YPLANE = MT * 16 * FOUT * 2;
  constexpr int FPW = (MT * KBA) / 8;
  constexpr int C2 = 2 * FOUT;

  __shared__ alignas(16) char s_mem[YPLANE];
  __shared__ int s_gsrc[MT * 16];
  __shared__ int s_code[MT * 16];

  int tid = threadIdx.x;
  int lane = tid & 63;
  int w = tid >> 6;
  int lg = lane >> 4;
  int ln = lane & 15;
  int pgbase = blockIdx.x * MT;

  if (tid < MT * 16) {
    int pg = pgbase + (tid >> 4);
    int b = pg >> 11;
    s_gsrc[tid] = b * 2048 + idx[pg * KK + (tid & 15)];
    s_code[tid] = acode[pg * KK + (tid & 15)];
  }
  __syncthreads();

#pragma unroll
  for (int r = 0; r < FPW; ++r) {
    int f = w * FPW + r;
    int mt = f / KBA, kb = f % KBA;
    int row = mt * 16 + ln;
    int col = kb * 32 + lg * 8;
    const float* up = uv + (size_t)s_gsrc[row] * C2 + col;
    const float* cp = uv + (size_t)(pgbase + mt) * C2 + FOUT + col;
    float4 u0 = *(const float4*)up;
    float4 u1 = *(const float4*)(up + 4);
    float4 v0 = *(const float4*)cp;
    float4 v1 = *(const float4*)(cp + 4);
    float uu[8] = {u0.x, u0.y, u0.z, u0.w, u1.x, u1.y, u1.z, u1.w};
    float vv[8] = {v0.x, v0.y, v0.z, v0.w, v1.x, v1.y, v1.z, v1.w};
    unsigned short oh[8];
#pragma unroll
    for (int i = 0; i < 8; ++i) {
      float t = uu[i] + vv[i];
      t = (t >= 0.f) ? t : NEGS * t;
      oh[i] = bfh(t);
    }
    *(u16x8*)(s_mem + (f * 64 + lane) * 16) = *(u16x8*)oh;
  }
  __syncthreads();

  attn_phase<FOUT, MT>(s_mem, s_code, xh, pgbase, w, lane, attnh, attnl, coef, ooff);
}

// ---------------------------------------------------------------- layer 1 (PE + conv + attn, MT=4)
__global__ __launch_bounds__(512, 4) void k_layer1(
    unsigned short* xh, const float* __restrict__ rel, const int* __restrict__ idx,
    const int* __restrict__ acode,
    const unsigned short* __restrict__ convh, const unsigned short* __restrict__ convl,
    const unsigned short* __restrict__ attnh, const unsigned short* __restrict__ attnl,
    const float* __restrict__ bng, const float* __restrict__ bnb,
    const float* __restrict__ coef, int ooff) {
  constexpr int FOUT = 64;
  constexpr int KB = 2;     // K_TOT=64
  constexpr int KBA = 2;
  constexpr int YPLANE = 64 * FOUT * 2;  // 8KB

  __shared__ alignas(16) char s_mem[YPLANE];
  __shared__ int s_gsrc[64];
  __shared__ int s_code[64];

  int tid = threadIdx.x;
  int lane = tid & 63;
  int w = tid >> 6;
  int lg = lane >> 4;
  int ln = lane & 15;
  int pgbase = blockIdx.x * 4;

  if (tid < 64) {
    int pg = pgbase + (tid >> 4);
    int b = pg >> 11;
    s_gsrc[tid] = b * 2048 + idx[pg * KK + (tid & 15)];
    s_code[tid] = acode[pg * KK + (tid & 15)];
  }
  __syncthreads();

  {
    int smt = w >> 1, skb = w & 1;
    float rc = rel[((size_t)(pgbase + smt) * KK + ln) * 2 + skb];
    unsigned short hb[8];
#pragma unroll
    for (int i = 0; i < 8; ++i) {
      int j = lg * 8 + i;
      int fidx = j & 15;
      float freq = exp2f(-(float)fidx * 0.8304820237218406f);  // 10000^(-fidx/16)
      float ang = rc * freq;
      float v = (j < 16) ? __sinf(ang) : __cosf(ang);
      hb[i] = bfh(v);
    }
    *(u16x8*)(s_mem + ((w * 64 + lane) * 16)) = *(u16x8*)hb;
  }
  __syncthreads();

  int wr = w >> 2, wc = w & 3;
  f32x4 cacc[2];
  cacc[0] = (f32x4){0.f, 0.f, 0.f, 0.f};
  cacc[1] = (f32x4){0.f, 0.f, 0.f, 0.f};
#pragma unroll
  for (int ks = 0; ks < 2; ++ks) {
    s16x8 ah[2];
#pragma unroll
    for (int m = 0; m < 2; ++m) {
      int by = (((wr * 2 + m) * 2 + ks) * 64 + lane) * 16;
      ah[m] = *(const s16x8*)(s_mem + by);
    }
    __builtin_amdgcn_s_setprio(1);
    size_t fo = ((size_t)wc * KB + ks) * 64 + lane;
    s16x8 bh = ((const s16x8*)convh)[fo];
    s16x8 bl = ((const s16x8*)convl)[fo];
#pragma unroll
    for (int m = 0; m < 2; ++m) {
      cacc[m] = mfma16(ah[m], bh, cacc[m]);
      cacc[m] = mfma16(ah[m], bl, cacc[m]);
    }
    __builtin_amdgcn_s_setprio(0);
  }
  __syncthreads();

  {
    int g = wc * 16 + ln;
    float sc = bng[g] * INVS;
    float bs = bnb[g];
    int gpart = ((g >> 5) * 64 + ((g >> 3) & 3) * 16) * 16 + (g & 7) * 2;
#pragma unroll
    for (int m = 0; m < 2; ++m) {
#pragma unroll
      for (int reg = 0; reg < 4; ++reg) {
        int r = wr * 32 + m * 16 + lg * 4 + reg;
        float v = cacc[m][reg] * sc + bs;
        v = (v >= 0.f) ? v : NEGS * v;
        int by = (r >> 4) * (KBA * 1024) + gpart + (r & 15) * 16;
        *(unsigned short*)(s_mem + by) = bfh(v);
      }
    }
  }
  __syncthreads();

  attn_phase<64, 4>(s_mem, s_code, xh, pgbase, w, lane, attnh, attnl, coef, ooff);
}

// ---------------------------------------------------------------- conv5 GEMM (256x64 blocks, m=8 j=1)
__global__ __launch_bounds__(512, 2) void k_gemm5_m(const unsigned short* __restrict__ xh,
                                                    const unsigned short* __restrict__ bph,
                                                    const unsigned short* __restrict__ bpl,
                                                    const float* __restrict__ g5,
                                                    const float* __restrict__ b5,
                                                    float* __restrict__ pmax,
                                                    float* __restrict__ psum) {
  __shared__ alignas(16) char s_mem[65536];  // 2 x 32KB A dbuf
  int tid = threadIdx.x;
  int lane = tid & 63;
  int w = tid >> 6;
  int lg = lane >> 4;
  int ln = lane & 15;
  int bm = blockIdx.x, bn = blockIdx.y;
  int wm = w >> 2, wn = w & 3;
  f32x4 acc[8];
#pragma unroll
  for (int m = 0; m < 8; ++m) acc[m] = (f32x4){0.f, 0.f, 0.f, 0.f};

  int sr = w * 16 + ln;
  const unsigned short* gH = xh + (size_t)(bm * 256 + sr) * 2048 + lg * 8;
  const unsigned short* gH2 = gH + (size_t)128 * 2048;
  int fm = sr >> 4;
  int fl = lg * 16 + (sr & 15);
  int wbyA = ((fm * 2 + 0) * 64 + fl) * 16;
  int wbyB = ((fm * 2 + 1) * 64 + fl) * 16;
  int wbyC = (((fm + 8) * 2 + 0) * 64 + fl) * 16;
  int wbyD = (((fm + 8) * 2 + 1) * 64 + fl) * 16;
  u16x8 h0, h1, h2, h3;
  auto load4 = [&](int ch) {
    h0 = *(const u16x8*)(gH + ch * 64);
    h1 = *(const u16x8*)(gH + ch * 64 + 32);
    h2 = *(const u16x8*)(gH2 + ch * 64);
    h3 = *(const u16x8*)(gH2 + ch * 64 + 32);
  };
  load4(0);
  *(u16x8*)(s_mem + wbyA) = h0;
  *(u16x8*)(s_mem + wbyB) = h1;
  *(u16x8*)(s_mem + wbyC) = h2;
  *(u16x8*)(s_mem + wbyD) = h3;
  __syncthreads();
  int p = 0;
  for (int ch = 0; ch < 32; ++ch) {
    if (ch + 1 < 32) load4(ch + 1);
#pragma unroll
    for (int ks = 0; ks < 2; ++ks) {
      s16x8 ah[8];
#pragma unroll
      for (int m = 0; m < 8; ++m) {
        int by = p * 32768 + (((wm * 8 + m) * 2 + ks) * 64 + lane) * 16;
        ah[m] = *(const s16x8*)(s_mem + by);
      }
      int kb = ch * 2 + ks;
      __builtin_amdgcn_s_setprio(1);
      {
        size_t fo = ((size_t)(bn * 4 + wn) * 64 + kb) * 64 + lane;
        s16x8 bh = ((const s16x8*)bph)[fo];
        s16x8 bl = ((const s16x8*)bpl)[fo];
#pragma unroll
        for (int m = 0; m < 8; ++m) {
          acc[m] = mfma16(ah[m], bh, acc[m]);
          acc[m] = mfma16(ah[m], bl, acc[m]);
        }
      }
      __builtin_amdgcn_s_setprio(0);
    }
    if (ch + 1 < 32) {
      int d = (p ^ 1) * 32768;
      *(u16x8*)(s_mem + d + wbyA) = h0;
      *(u16x8*)(s_mem + d + wbyB) = h1;
      *(u16x8*)(s_mem + d + wbyC) = h2;
      *(u16x8*)(s_mem + d + wbyD) = h3;
      p ^= 1;
    }
    __syncthreads();
  }

  float cmax, csum;
  {
    int g = bn * 64 + wn * 16 + ln;
    float sc = g5[g] * INVS;
    float bs = b5[g];
    float mx = -3.0e38f, sm = 0.f;
#pragma unroll
    for (int m = 0; m < 8; ++m)
#pragma unroll
      for (int reg = 0; reg < 4; ++reg) {
        float v = acc[m][reg] * sc + bs;
        v = (v >= 0.f) ? v : NEGS * v;
        mx = fmaxf(mx, v);
        sm += v;
      }
    mx = fmaxf(mx, __shfl_xor(mx, 16, 64));
    mx = fmaxf(mx, __shfl_xor(mx, 32, 64));
    sm += __shfl_xor(sm, 16, 64);
    sm += __shfl_xor(sm, 32, 64);
    cmax = mx;
    csum = sm;
  }
  float* s_f = (float*)s_mem;  // [2 wm][64 col][2]
  if (lg == 0) {
    int col = wn * 16 + ln;
    s_f[(wm * 64 + col) * 2 + 0] = cmax;
    s_f[(wm * 64 + col) * 2 + 1] = csum;
  }
  __syncthreads();
  if (tid < 64) {
    float mx = fmaxf(s_f[tid * 2], s_f[(64 + tid) * 2]);
    float sm = s_f[tid * 2 + 1] + s_f[(64 + tid) * 2 + 1];
    pmax[(size_t)bm * 1024 + bn * 64 + tid] = mx;
    psum[(size_t)bm * 1024 + bn * 64 + tid] = sm;
  }
}

// ---------------------------------------------------------------- feat + heads (parallel grids)
__global__ __launch_bounds__(256) void k_feat(const float* __restrict__ pmax,
                                              const float* __restrict__ psum,
                                              float* __restrict__ feat) {
  int t = blockIdx.x * 256 + threadIdx.x;
  if (t >= BB * 1024) return;
  int b = t >> 10, o = t & 1023;
  float mx = -3.0e38f, sm = 0.f;
  for (int i = 0; i < 8; ++i) {
    mx = fmaxf(mx, pmax[(size_t)(b * 8 + i) * 1024 + o]);
    sm += psum[(size_t)(b * 8 + i) * 1024 + o];
  }
  feat[b * 2048 + o] = mx;
  feat[b * 2048 + 1024 + o] = sm * (1.0f / NN);
}

template <bool HASB, bool DOBN, bool ACT>
__global__ __launch_bounds__(256) void k_head(const float* __restrict__ X,
                                              const float* __restrict__ Wm,
                                              const float* __restrict__ bias,
                                              const float* __restrict__ g,
                                              const float* __restrict__ bb,
                                              float* __restrict__ Y, int IN, int ON) {
  int gt = blockIdx.x * 256 + threadIdx.x;
  int w = gt >> 6, lane = gt & 63;
  if (w >= BB * ON) return;
  int b = w / ON, o = w - b * ON;
  const float* x = X + (size_t)b * IN;
  const float* wr = Wm + (size_t)o * IN;
  float s = 0.f;
  for (int c = lane; c < IN; c += 64) s += x[c] * wr[c];
#pragma unroll
  for (int off = 32; off > 0; off >>= 1) s += __shfl_down(s, off, 64);
  if (lane == 0) {
    if (HASB) s += bias[o];
    if (DOBN) s = s * INVS * g[o] + bb[o];
    if (ACT) s = (s >= 0.f) ? s : NEGS * s;
    Y[(size_t)b * ON + o] = s;
  }
}

// ---------------------------------------------------------------- launch
extern "C" void kernel_launch(void* const* d_in, const int* in_sizes, int n_in,
                              void* d_out, int out_size, void* d_ws, size_t ws_size,
                              hipStream_t stream) {
  const float* pos = (const float*)d_in[0];
  const int* types = (const int*)d_in[1];
  const float* conv1_w = (const float*)d_in[2];
  const float* bn1_g = (const float*)d_in[3];
  const float* bn1_b = (const float*)d_in[4];
  const float* W1 = (const float*)d_in[5];
  const float* ap1 = (const float*)d_in[6];
  const float* as1 = (const float*)d_in[7];
  const float* conv2_w = (const float*)d_in[8];
  const float* bn2_g = (const float*)d_in[9];
  const float* bn2_b = (const float*)d_in[10];
  const float* W2 = (const float*)d_in[11];
  const float* ap2 = (const float*)d_in[12];
  const float* as2 = (const float*)d_in[13];
  const float* conv3_w = (const float*)d_in[14];
  const float* bn3_g = (const float*)d_in[15];
  const float* bn3_b = (const float*)d_in[16];
  const float* W3 = (const float*)d_in[17];
  const float* ap3 = (const float*)d_in[18];
  const float* as3 = (const float*)d_in[19];
  const float* conv4_w = (const float*)d_in[20];
  const float* bn4_g = (const float*)d_in[21];
  const float* bn4_b = (const float*)d_in[22];
  const float* W4 = (const float*)d_in[23];
  const float* ap4 = (const float*)d_in[24];
  const float* as4 = (const float*)d_in[25];
  const float* conv5_w = (const float*)d_in[26];
  const float* bn5_g = (const float*)d_in[27];
  const float* bn5_b = (const float*)d_in[28];
  const float* lin1_w = (const float*)d_in[29];
  const float* bn6_g = (const float*)d_in[30];
  const float* bn6_b = (const float*)d_in[31];
  const float* lin2_w = (const float*)d_in[32];
  const float* lin2_b = (const float*)d_in[33];
  const float* bn7_g = (const float*)d_in[34];
  const float* bn7_b = (const float*)d_in[35];
  const float* lin3_w = (const float*)d_in[36];
  const float* lin3_b = (const float*)d_in[37];
  (void)in_sizes; (void)n_in; (void)out_size; (void)ws_size;

  float* ws = (float*)d_ws;
  size_t off = 0;
  auto take = [&](size_t nf) {
    float* p = ws + off;
    off += (nf + 63) & ~(size_t)63;
    return p;
  };
  auto takeu = [&](size_t nu) { return (unsigned short*)take((nu + 1) / 2); };

  int* idx = (int*)take(BB * NN * KK);
  int* acode = (int*)take(BB * NN * KK);
  float* rel = take((size_t)BB * NN * KK * 2);
  unsigned short* xh = takeu((size_t)BB * NN * 2048);
  float* uv = take((size_t)4096 * 512);
  float* pmax = take(16 * 1024);
  float* psum = take(16 * 1024);
  float* feat = take(BB * 2048);
  float* h1 = take(BB * 512);
  float* h2 = take(BB * 256);
  unsigned short* c1h = takeu(64 * 64);
  unsigned short* c1l = takeu(64 * 64);
  unsigned short* uvw2h = takeu(256 * 128);
  unsigned short* uvw2l = takeu(256 * 128);
  unsigned short* uvw3h = takeu(256 * 256);
  unsigned short* uvw3l = takeu(256 * 256);
  unsigned short* uvw4h = takeu(512 * 512);
  unsigned short* uvw4l = takeu(512 * 512);
  unsigned short* a1h = takeu(4 * 64 * 64);
  unsigned short* a1l = takeu(4 * 64 * 64);
  unsigned short* a2h = takeu(4 * 64 * 64);
  unsigned short* a2l = takeu(4 * 64 * 64);
  unsigned short* a3h = takeu(4 * 128 * 128);
  unsigned short* a3l = takeu(4 * 128 * 128);
  unsigned short* a4h = takeu(4 * 256 * 256);
  unsigned short* a4l = takeu(4 * 256 * 256);
  unsigned short* g5h = takeu((size_t)2048 * 1024);
  unsigned short* g5l = takeu((size_t)2048 * 1024);
  float* coef1 = take(4 * 44 * 64);
  float* coef2 = take(4 * 44 * 64);
  float* coef3 = take(4 * 44 * 128);
  float* coef4 = take(4 * 44 * 256);

  dim3 blk(256);
  dim3 blk5(512);

  PackArgs pa;
  // {src, dh, dl, KB, NT, srcld, Cdiff, mode, sstride, dstride, nrep, bpr}
  pa.d[0] = {conv1_w, c1h, c1l, 2, 4, 64, 0, 1, 0, 0, 1, 2};
  pa.d[1] = {conv2_w, uvw2h, uvw2l, 8, 4, 512, 0, 1, 0, 0, 1, 8};
  pa.d[2] = {conv2_w, uvw2h + 16384, uvw2l + 16384, 8, 4, 512, 256, 2, 0, 0, 1, 8};
  pa.d[3] = {conv3_w, uvw3h, uvw3l, 8, 8, 512, 0, 1, 0, 0, 1, 16};
  pa.d[4] = {conv3_w, uvw3h + 32768, uvw3l + 32768, 8, 8, 512, 256, 2, 0, 0, 1, 16};
  pa.d[5] = {conv4_w, uvw4h, uvw4l, 16, 16, 1024, 0, 1, 0, 0, 1, 64};
  pa.d[6] = {conv4_w, uvw4h + 131072, uvw4l + 131072, 16, 16, 1024, 512, 2, 0, 0, 1, 64};
  pa.d[7] = {W1, a1h, a1l, 2, 4, 64, 0, 0, 4096, 4096, 4, 2};
  pa.d[8] = {W2, a2h, a2l, 2, 4, 64, 0, 0, 4096, 4096, 4, 2};
  pa.d[9] = {W3, a3h, a3l, 4, 8, 128, 0, 0, 16384, 16384, 4, 8};
  pa.d[10] = {W4, a4h, a4l, 8, 16, 256, 0, 0, 65536, 65536, 4, 32};
  pa.d[11] = {conv5_w, g5h, g5l, 64, 64, 2048, 0, 1, 0, 0, 1, 1024};
  pa.d[12] = {ap1, (unsigned short*)coef1, nullptr, 5, 1, 0, 2304, 3, 2304, 5632, 4, 2};
  pa.d[13] = {as1, (unsigned short*)(coef1 + 2304), nullptr, 1, 1, 0, 512, 3, 512, 5632, 4, 1};
  pa.d[14] = {ap2, (unsigned short*)coef2, nullptr, 5, 1, 0, 2304, 3, 2304, 5632, 4, 2};
  pa.d[15] = {as2, (unsigned short*)(coef2 + 2304), nullptr, 1, 1, 0, 512, 3, 512, 5632, 4, 1};
  pa.d[16] = {ap3, (unsigned short*)coef3, nullptr, 9, 1, 0, 4608, 3, 4608, 11264, 4, 3};
  pa.d[17] = {as3, (unsigned short*)(coef3 + 4608), nullptr, 2, 1, 0, 1024, 3, 1024, 11264, 4, 1};
  pa.d[18] = {ap4, (unsigned short*)coef4, nullptr, 18, 1, 0, 9216, 3, 9216, 22528, 4, 5};
  pa.d[19] = {as4, (unsigned short*)(coef4 + 9216), nullptr, 4, 1, 0, 2048, 3, 2048, 22528, 4, 1};
  k_megapack<<<dim3(1024, 20), blk, 0, stream>>>(pa);

  k_ballquery<<<dim3(BB * NN / 4), blk, 0, stream>>>(pos, types, idx, acode, rel);

  // layer 1
  k_layer1<<<dim3(BB * NN / 4), blk5, 0, stream>>>(
      xh, rel, idx, acode, c1h, c1l, a1h, a1l, bn1_g, bn1_b, coef1, 0);

  // layer 2
  k_pregemm<8, 4><<<dim3(32, 2), blk5, 0, stream>>>(
      xh, 0, uvw2h, uvw2l, bn2_g, bn2_b, uv, 64);
  k_attn<64><<<dim3(BB * NN / 8), blk5, 0, stream>>>(
      xh, uv, idx, acode, a2h, a2l, coef2, 256);

  // layer 3
  k_pregemm<8, 8><<<dim3(32, 2), blk5, 0, stream>>>(
      xh, 256, uvw3h, uvw3l, bn3_g, bn3_b, uv, 128);
  k_attn<128><<<dim3(BB * NN / 8), blk5, 0, stream>>>(
      xh, uv, idx, acode, a3h, a3l, coef3, 512);

  // layer 4
  k_pregemm<16, 8><<<dim3(32, 4), blk5, 0, stream>>>(
      xh, 512, uvw4h, uvw4l, bn4_g, bn4_b, uv, 256);
  k_attn<256><<<dim3(BB * NN / 8), blk5, 0, stream>>>(
      xh, uv, idx, acode, a4h, a4l, coef4, 1024);

  // conv5 + pooled partials + parallel tail
  k_gemm5_m<<<dim3(16, 16), blk5, 0, stream>>>(xh, g5h, g5l, bn5_g, bn5_b, pmax, psum);
  k_feat<<<dim3(8), blk, 0, stream>>>(pmax, psum, feat);
  k_head<false, true, true><<<dim3(BB * 512 * 64 / 256), blk, 0, stream>>>(
      feat, lin1_w, nullptr, bn6_g, bn6_b, h1, 2048, 512);
  k_head<true, true, true><<<dim3(BB * 256 * 64 / 256), blk, 0, stream>>>(
      h1, lin2_w, lin2_b, bn7_g, bn7_b, h2, 512, 256);
  k_head<true, false, false><<<dim3(1), blk, 0, stream>>>(
      h2, lin3_w, lin3_b, nullptr, nullptr, (float*)d_out, 256, 2);
}